// Round 13
// baseline (590.689 us; speedup 1.0000x reference)
//
#include <hip/hip_runtime.h>
#include <hip/hip_bf16.h>
#include <cstdint>
#include <cstddef>

#define B_SZ   2
#define T_CTX  2048
#define DIM_C  1024
#define NHEAD  16
#define HD     64
#define NBH    (B_SZ*NHEAD)

typedef __attribute__((ext_vector_type(8))) short short8;
typedef __attribute__((ext_vector_type(4))) float f32x4;
typedef __attribute__((ext_vector_type(16))) float f32x16;

union BV8 { short8 s; __hip_bfloat16 h[8]; unsigned short u[8]; };
union U32x4 { uint32_t u[4]; short8 s8; };

#define GLD16(gp, lp) \
  __builtin_amdgcn_global_load_lds((const __attribute__((address_space(1))) void*)(gp), \
                                   (__attribute__((address_space(3))) void*)(lp), 16, 0, 0)

// pack two f32 -> bf16 pair (lo = first arg), pure IR (hazard-safe feed into MFMA)
__device__ inline uint32_t pkbf(float a, float b) {
  union { __hip_bfloat16 h; unsigned short u; } ua, ub;
  ua.h = __float2bfloat16(a);
  ub.h = __float2bfloat16(b);
  return ((uint32_t)ub.u << 16) | (uint32_t)ua.u;
}

// ---------------- fp32 -> bf16 convert ----------------
__global__ __launch_bounds__(256) void cvt_f32_bf16(const float* __restrict__ in,
                                                    __hip_bfloat16* __restrict__ out,
                                                    int n4) {
  int i = blockIdx.x * 256 + threadIdx.x;
  if (i >= n4) return;
  float4 v = reinterpret_cast<const float4*>(in)[i];
  BV8 o;
  o.h[0] = __float2bfloat16(v.x);
  o.h[1] = __float2bfloat16(v.y);
  o.h[2] = __float2bfloat16(v.z);
  o.h[3] = __float2bfloat16(v.w);
  ushort4 st = { o.u[0], o.u[1], o.u[2], o.u[3] };
  reinterpret_cast<ushort4*>(out)[i] = st;
}

// ---------------- bf16 GEMM, C = A[M,K] * Bt[N,K]^T (XCD-swizzled blocks) ----------------
template <typename OutT>
__global__ __launch_bounds__(256) void gemm_bt(const __hip_bfloat16* __restrict__ A,
                                               const __hip_bfloat16* __restrict__ Bt,
                                               OutT* __restrict__ C,
                                               int M, int N, int K) {
  __shared__ __align__(16) __hip_bfloat16 As[128 * 32];
  __shared__ __align__(16) __hip_bfloat16 Bs[128 * 32];
  const int tid = threadIdx.x;
  const int w = tid >> 6, l = tid & 63;
  const int l15 = l & 15, l4 = l >> 4;
  const int wr = w >> 1, wc = w & 1;
  // T1: bijective XCD chunking (requires nwg % 8 == 0)
  const int gx = (int)gridDim.x;
  const int nwg = gx * (int)gridDim.y;
  int lin = (int)blockIdx.y * gx + (int)blockIdx.x;
  lin = (lin & 7) * (nwg >> 3) + (lin >> 3);
  const long bm = (long)(lin / gx) * 128;
  const long bn = (long)(lin % gx) * 128;

  f32x4 acc[4][4] = {};

  const int srow = tid >> 2;
  const int scol = (tid & 3) * 16;
  char* AsB = (char*)As;
  char* BsB = (char*)Bs;
  const char* Ab  = (const char*)A;
  const char* Btb = (const char*)Bt;

  for (int kt = 0; kt < K; kt += 32) {
    __syncthreads();
#pragma unroll
    for (int it = 0; it < 2; ++it) {
      long arow = bm + it * 64 + srow;
      GLD16(Ab + (arow * K + kt) * 2 + scol, AsB + it * 4096 + w * 1024);
      long brow = bn + it * 64 + srow;
      GLD16(Btb + (brow * K + kt) * 2 + scol, BsB + it * 4096 + w * 1024);
    }
    __syncthreads();
    short8 aF[4], bF[4];
#pragma unroll
    for (int m = 0; m < 4; ++m)
      aF[m] = *(const short8*)(AsB + (wr * 64 + m * 16 + l15) * 64 + l4 * 16);
#pragma unroll
    for (int n = 0; n < 4; ++n)
      bF[n] = *(const short8*)(BsB + (wc * 64 + n * 16 + l15) * 64 + l4 * 16);
#pragma unroll
    for (int m = 0; m < 4; ++m)
#pragma unroll
      for (int n = 0; n < 4; ++n)
        acc[m][n] = __builtin_amdgcn_mfma_f32_16x16x32_bf16(aF[m], bF[n], acc[m][n], 0, 0, 0);
  }

#pragma unroll
  for (int m = 0; m < 4; ++m)
#pragma unroll
    for (int n = 0; n < 4; ++n)
#pragma unroll
      for (int r = 0; r < 4; ++r) {
        long row = bm + wr * 64 + m * 16 + l4 * 4 + r;
        long col = bn + wc * 64 + n * 16 + l15;
        float v = acc[m][n][r];
        if constexpr (sizeof(OutT) == 2) {
          C[row * N + col] = __float2bfloat16(v);
        } else {
          C[row * N + col] = v;
        }
      }
}

// ---------------- fused qkv GEMM + RoPE epilogue ----------------
// C = xb[4096,1024] @ wqkvb[3072,1024]^T. Region by bn: [0,1024)=Q, [1024,2048)=K, else V.
// Q/K: RoPE applied in-register (pair exchange via shfl_xor(acc,1); both pair-lanes share
// the angle since i = d>>1), written directly to Qb/Kb [bh][t][64]. Q folds 0.125*log2e.
// V: plain bf16 to Vtmp[4096][1024] (transposed to VTb by v_pack).
__global__ __launch_bounds__(256) void gemm_qkv_rope(const __hip_bfloat16* __restrict__ A,
                                                     const __hip_bfloat16* __restrict__ Bt,
                                                     __hip_bfloat16* __restrict__ Qb,
                                                     __hip_bfloat16* __restrict__ Kb,
                                                     __hip_bfloat16* __restrict__ Vtmp) {
  __shared__ __align__(16) __hip_bfloat16 As[128 * 32];
  __shared__ __align__(16) __hip_bfloat16 Bs[128 * 32];
  const int tid = threadIdx.x;
  const int w = tid >> 6, l = tid & 63;
  const int l15 = l & 15, l4 = l >> 4;
  const int wr = w >> 1, wc = w & 1;
  // T1: 768 blocks (24 x 32), chunk 96 per XCD
  int lin = (int)blockIdx.y * 24 + (int)blockIdx.x;
  lin = (lin & 7) * 96 + (lin >> 3);
  const long bm = (long)(lin / 24) * 128;
  const long bn = (long)(lin % 24) * 128;

  f32x4 acc[4][4] = {};

  const int srow = tid >> 2;
  const int scol = (tid & 3) * 16;
  char* AsB = (char*)As;
  char* BsB = (char*)Bs;
  const char* Ab  = (const char*)A;
  const char* Btb = (const char*)Bt;

  for (int kt = 0; kt < 1024; kt += 32) {
    __syncthreads();
#pragma unroll
    for (int it = 0; it < 2; ++it) {
      long arow = bm + it * 64 + srow;
      GLD16(Ab + (arow * 1024 + kt) * 2 + scol, AsB + it * 4096 + w * 1024);
      long brow = bn + it * 64 + srow;
      GLD16(Btb + (brow * 1024 + kt) * 2 + scol, BsB + it * 4096 + w * 1024);
    }
    __syncthreads();
    short8 aF[4], bF[4];
#pragma unroll
    for (int m = 0; m < 4; ++m)
      aF[m] = *(const short8*)(AsB + (wr * 64 + m * 16 + l15) * 64 + l4 * 16);
#pragma unroll
    for (int n = 0; n < 4; ++n)
      bF[n] = *(const short8*)(BsB + (wc * 64 + n * 16 + l15) * 64 + l4 * 16);
#pragma unroll
    for (int m = 0; m < 4; ++m)
#pragma unroll
      for (int n = 0; n < 4; ++n)
        acc[m][n] = __builtin_amdgcn_mfma_f32_16x16x32_bf16(aF[m], bF[n], acc[m][n], 0, 0, 0);
  }

  const int region = (int)(bn >> 10);  // 0=Q 1=K 2=V (block-uniform)
  if (region < 2) {
    __hip_bfloat16* dst = region ? Kb : Qb;
    const float qs = region ? 1.0f : 0.125f * 1.4426950408889634f;
    const int h = ((int)(bn & 1023) >> 6) + wc;  // head (block/wave-uniform)
#pragma unroll
    for (int n = 0; n < 4; ++n) {
      const int d = n * 16 + l15;  // 0..63 within head
      const float inv = exp2f(-13.287712379549449f *
                              ((float)(2 * (d >> 1)) * (1.0f / 64.0f)));
#pragma unroll
      for (int m = 0; m < 4; ++m) {
#pragma unroll
        for (int r = 0; r < 4; ++r) {
          const int tg = (int)bm + wr * 64 + m * 16 + l4 * 4 + r;
          const int b = tg >> 11, t = tg & 2047;
          float sn, cn;
          sincosf((float)t * inv, &sn, &cn);
          const float x = acc[m][n][r];
          const float px = __shfl_xor(x, 1);  // pair partner (same angle)
          const float o = ((l15 & 1) ? (px * sn + x * cn) : (x * cn - px * sn)) * qs;
          dst[((size_t)(((b << 4) + h) * 2048 + t)) * 64 + d] = __float2bfloat16(o);
        }
      }
    }
  } else {
    const int colv = (int)(bn & 1023) + wc * 64;
#pragma unroll
    for (int m = 0; m < 4; ++m)
#pragma unroll
      for (int n = 0; n < 4; ++n)
#pragma unroll
        for (int r = 0; r < 4; ++r) {
          const int tg = (int)bm + wr * 64 + m * 16 + l4 * 4 + r;
          Vtmp[(size_t)tg * 1024 + colv + n * 16 + l15] = __float2bfloat16(acc[m][n][r]);
        }
  }
}

// ---------------- V transpose: Vtmp[b*2048+t][h*64+d] -> VTb[bh][d][t] ----------------
__global__ __launch_bounds__(256) void v_pack(const __hip_bfloat16* __restrict__ Vtmp,
                                              __hip_bfloat16* __restrict__ VTb) {
  __shared__ __hip_bfloat16 vt[64][72];
  const int bh = blockIdx.x;
  const int b = bh >> 4, h = bh & 15;
  const int t0 = blockIdx.y * 64;
  const int tid = threadIdx.x;

#pragma unroll
  for (int rep = 0; rep < 2; ++rep) {
    int idx = rep * 256 + tid;
    int tt = idx >> 3;
    int d0 = (idx & 7) * 8;
    int t = t0 + tt;
    BV8 vv;
    vv.s = *(const short8*)(Vtmp + ((size_t)(b * T_CTX + t)) * 1024 + h * 64 + d0);
#pragma unroll
    for (int j = 0; j < 8; ++j) vt[d0 + j][tt] = vv.h[j];
  }
  __syncthreads();
#pragma unroll
  for (int rep = 0; rep < 2; ++rep) {
    int idx = rep * 256 + tid;
    int d = idx >> 3;
    int toff = (idx & 7) * 8;
    BV8 o;
#pragma unroll
    for (int j = 0; j < 8; ++j) o.h[j] = vt[d][toff + j];
    *(short8*)(VTb + ((size_t)bh * 64 + d) * T_CTX + t0 + toff) = o.s;
  }
}

// ---------------- flash attention (causal), 32x32 MFMA, paired-tile barriers ----------------
// (unchanged from round 12: 4 waves = qsub x kh, 64-row balanced slab pairs, k-split,
// fixed-base exp2 softmax, end-of-kernel merge, two KV tiles per barrier)
__global__ __launch_bounds__(256) void flash_attn(const __hip_bfloat16* __restrict__ Qb,
                                                  const __hip_bfloat16* __restrict__ Kb,
                                                  const __hip_bfloat16* __restrict__ VTb,
                                                  __hip_bfloat16* __restrict__ Y) {
  __shared__ __align__(16) char smem[65536];
  const int bh = blockIdx.x;
  const int b = bh >> 4, h = bh & 15;
  const int y = blockIdx.y;
  const int jA = 31 - y;
  const int jB = y;
  const int tid = threadIdx.x;
  const int w = tid >> 6, l = tid & 63;
  const int qsub = w >> 1, kh = w & 1;
  const int l31 = l & 31, hh = l >> 5;
  const int sw7 = (l31 & 7) << 4;
  const int rowb = tid >> 3;
  const int colS = (tid & 7) * 16;

#define STAGE1(gg)                                                                     \
  {                                                                                    \
    const int tt_ = ((gg) <= jA) ? (gg) : (gg) - jA - 1;                               \
    const int kv0_ = tt_ << 6;                                                         \
    char* base_ = smem + (((gg) >> 1) & 1) * 32768 + ((gg) & 1) * 16384;               \
    _Pragma("unroll")                                                                  \
    for (int rnd = 0; rnd < 2; ++rnd) {                                                \
      int row = rnd * 32 + rowb;                                                       \
      int sw = colS ^ ((row & 7) << 4);                                                \
      GLD16((const char*)Kb + (((size_t)bh * T_CTX + kv0_ + row) << 7) + sw,           \
            base_ + rnd * 4096 + w * 1024);                                            \
      GLD16((const char*)VTb + ((((size_t)bh * 64 + row) * T_CTX + kv0_) << 1) + sw,   \
            base_ + 8192 + rnd * 4096 + w * 1024);                                     \
    }                                                                                  \
  }

  f32x16 oA0 = {}, oA1 = {}, oB0 = {}, oB1 = {};
  float lrA = 0.0f, lrB = 0.0f;

  STAGE1(0)
  STAGE1(1)

  int rr = 0;
#pragma unroll
  for (int ph = 0; ph < 2; ++ph) {
    const int j = ph ? jB : jA;
    const int qglob = j * 64 + qsub * 32 + l31;
    f32x16& od0 = ph ? oB0 : oA0;
    f32x16& od1 = ph ? oB1 : oA1;
    float& lrw = ph ? lrB : lrA;

    short8 qB[4];
#pragma unroll
    for (int dblk = 0; dblk < 4; ++dblk)
      qB[dblk] = *(const short8*)(Qb + ((size_t)bh * T_CTX + qglob) * 64 + dblk * 16 + hh * 8);

    for (int t = 0; t <= j; ++t, ++rr) {
      if ((rr & 1) == 0) {
        __syncthreads();
        if (rr + 2 <= 32) STAGE1(rr + 2)
        if (rr + 3 <= 32) STAGE1(rr + 3)
      }
      const char* KsB = smem + ((rr >> 1) & 1) * 32768 + (rr & 1) * 16384;
      const char* VsB = KsB + 8192;
      const int kv0 = t << 6;
      const bool lastT = (t == j);

      if (!(lastT && kh > qsub)) {
        short8 kA[4];
#pragma unroll
        for (int dblk = 0; dblk < 4; ++dblk)
          kA[dblk] = *(const short8*)(KsB + (kh * 32 + l31) * 128 + ((dblk * 32 + hh * 16) ^ sw7));
        short8 vA[2][2];
#pragma unroll
        for (int dt = 0; dt < 2; ++dt)
#pragma unroll
          for (int ks = 0; ks < 2; ++ks)
            vA[dt][ks] = *(const short8*)(VsB + (dt * 32 + l31) * 128 +
                                          ((kh * 64 + ks * 32 + hh * 16) ^ sw7));

        f32x16 sT = {};
#pragma unroll
        for (int dblk = 0; dblk < 4; ++dblk) {
          __builtin_amdgcn_s_setprio(1);
          sT = __builtin_amdgcn_mfma_f32_32x32x16_bf16(kA[dblk], qB[dblk], sT, 0, 0, 0);
          __builtin_amdgcn_s_setprio(0);
        }
        if (lastT && kh == qsub) {
          const int kbase = kv0 + kh * 32 + 4 * hh;
#pragma unroll
          for (int r = 0; r < 16; ++r) {
            int kg = kbase + (r & 3) + 8 * (r >> 2);
            sT[r] = (kg > qglob) ? -1e30f : sT[r];
          }
        }
        float s8[8];
#pragma unroll
        for (int i = 0; i < 8; ++i) {
          sT[i]     = __builtin_amdgcn_exp2f(sT[i]);
          sT[i + 8] = __builtin_amdgcn_exp2f(sT[i + 8]);
          s8[i] = sT[i] + sT[i + 8];
        }
        float ps = ((s8[0] + s8[1]) + (s8[2] + s8[3])) + ((s8[4] + s8[5]) + (s8[6] + s8[7]));
        ps += __shfl_xor(ps, 32);
        lrw += ps;
        uint32_t wk[8];
#pragma unroll
        for (int i = 0; i < 8; ++i) wk[i] = pkbf(sT[2 * i], sT[2 * i + 1]);
#pragma unroll
        for (int ks = 0; ks < 2; ++ks) {
          const int base = ks * 4;
          uint32_t own0 = wk[base + 0], own1 = wk[base + 1];
          uint32_t own2 = wk[base + 2], own3 = wk[base + 3];
          uint32_t e0 = (uint32_t)__shfl_xor((int)(hh ? own0 : own2), 32);
          uint32_t e1 = (uint32_t)__shfl_xor((int)(hh ? own1 : own3), 32);
          U32x4 u;
          u.u[0] = hh ? e0 : own0;
          u.u[1] = hh ? e1 : own1;
          u.u[2] = hh ? own2 : e0;
          u.u[3] = hh ? own3 : e1;
          __builtin_amdgcn_s_setprio(1);
          od0 = __builtin_amdgcn_mfma_f32_32x32x16_bf16(vA[0][ks], u.s8, od0, 0, 0, 0);
          od1 = __builtin_amdgcn_mfma_f32_32x32x16_bf16(vA[1][ks], u.s8, od1, 0, 0, 0);
          __builtin_amdgcn_s_setprio(0);
        }
      }
    }
  }

  __syncthreads();
  {
    float* exch = (float*)smem;
    float* lst = exch + 8192;
    const int slotA = (0 * 2 + qsub) * 2 + kh;
    const int slotB = (1 * 2 + qsub) * 2 + kh;
    const f32x16& nA = kh ? oA0 : oA1;
    const f32x16& nB = kh ? oB0 : oB1;
#pragma unroll
    for (int m = 0; m < 4; ++m) {
      int c = ((2 * m + hh) ^ (l31 & 7)) * 4;
      f32x4 va, vb;
#pragma unroll
      for (int i = 0; i < 4; ++i) { va[i] = nA[m * 4 + i]; vb[i] = nB[m * 4 + i]; }
      *(f32x4*)(exch + slotA * 1024 + l31 * 32 + c) = va;
      *(f32x4*)(exch + slotB * 1024 + l31 * 32 + c) = vb;
    }
    if (hh == 0) {
      lst[slotA * 32 + l31] = lrA;
      lst[slotB * 32 + l31] = lrB;
    }
    __syncthreads();
    const int pA = (0 * 2 + qsub) * 2 + (kh ^ 1);
    const int pB = (1 * 2 + qsub) * 2 + (kh ^ 1);
    float ltA = lrA + lst[pA * 32 + l31];
    float ltB = lrB + lst[pB * 32 + l31];
    f32x16& ownA = kh ? oA1 : oA0;
    f32x16& ownB = kh ? oB1 : oB0;
#pragma unroll
    for (int m = 0; m < 4; ++m) {
      int c = ((2 * m + hh) ^ (l31 & 7)) * 4;
      f32x4 aA = *(const f32x4*)(exch + pA * 1024 + l31 * 32 + c);
      f32x4 aB = *(const f32x4*)(exch + pB * 1024 + l31 * 32 + c);
#pragma unroll
      for (int i = 0; i < 4; ++i) { ownA[m * 4 + i] += aA[i]; ownB[m * 4 + i] += aB[i]; }
    }
#pragma unroll
    for (int sl = 0; sl < 2; ++sl) {
      const f32x16& ov = sl ? ownB : ownA;
      float inv = 1.0f / (sl ? ltB : ltA);
      int q0s = (sl ? jB : jA) * 64 + qsub * 32;
      size_t rowoff = ((size_t)(b * T_CTX + q0s + l31)) * DIM_C + h * 64 + kh * 32;
#pragma unroll
      for (int m = 0; m < 4; ++m) {
        union { ushort4 v; unsigned short us[4]; } st;
#pragma unroll
        for (int i = 0; i < 4; ++i) {
          union { __hip_bfloat16 h2; unsigned short u; } cv;
          cv.h2 = __float2bfloat16(ov[m * 4 + i] * inv);
          st.us[i] = cv.u;
        }
        *(ushort4*)(Y + rowoff + 8 * m + 4 * hh) = st.v;
      }
    }
  }
#undef STAGE1
}

// ---------------- launcher ----------------
extern "C" void kernel_launch(void* const* d_in, const int* in_sizes, int n_in,
                              void* d_out, int out_size, void* d_ws, size_t ws_size,
                              hipStream_t stream) {
  const float* x     = (const float*)d_in[0];
  const float* qkv_w = (const float*)d_in[1];
  const float* out_w = (const float*)d_in[2];
  float* out = (float*)d_out;

  char* ws = (char*)d_ws;
  const size_t MB = 1024 * 1024;
  __hip_bfloat16* xb    = (__hip_bfloat16*)(ws + 0 * MB);
  __hip_bfloat16* wqkvb = (__hip_bfloat16*)(ws + 8 * MB);
  __hip_bfloat16* woutb = (__hip_bfloat16*)(ws + 14 * MB);
  __hip_bfloat16* Vtmp  = (__hip_bfloat16*)(ws + 16 * MB);  // 4096x1024 bf16 = 8MB
  __hip_bfloat16* Qb    = (__hip_bfloat16*)(ws + 40 * MB);
  __hip_bfloat16* Kb    = (__hip_bfloat16*)(ws + 48 * MB);
  __hip_bfloat16* VTb   = (__hip_bfloat16*)(ws + 56 * MB);
  __hip_bfloat16* yb    = (__hip_bfloat16*)(ws + 64 * MB);

  cvt_f32_bf16<<<4096, 256, 0, stream>>>(x, xb, 1048576);
  cvt_f32_bf16<<<3072, 256, 0, stream>>>(qkv_w, wqkvb, 786432);
  cvt_f32_bf16<<<1024, 256, 0, stream>>>(out_w, woutb, 262144);

  // fused qkv GEMM + RoPE: writes Qb/Kb directly; V to Vtmp
  gemm_qkv_rope<<<dim3(24, 32), 256, 0, stream>>>(xb, wqkvb, Qb, Kb, Vtmp);

  // V transpose only (16MB traffic vs rope_pack's 48MB)
  v_pack<<<dim3(NBH, 32), 256, 0, stream>>>(Vtmp, VTb);

  // 16 slab-pairs (31-y, y of 64-row slabs) x 32 bh = 512 blocks, 4 waves each
  flash_attn<<<dim3(NBH, 16), 256, 0, stream>>>(Qb, Kb, VTb, yb);

  gemm_bt<float><<<dim3(8, 32), 256, 0, stream>>>(yb, woutb, out, 4096, 1024, 1024);
}

// Round 14
// 140.472 us; speedup vs baseline: 4.2050x; 4.2050x over previous
//
#include <hip/hip_runtime.h>
#include <hip/hip_bf16.h>
#include <cstdint>
#include <cstddef>

#define B_SZ   2
#define T_CTX  2048
#define DIM_C  1024
#define NHEAD  16
#define HD     64
#define NBH    (B_SZ*NHEAD)

typedef __attribute__((ext_vector_type(8))) short short8;
typedef __attribute__((ext_vector_type(4))) float f32x4;
typedef __attribute__((ext_vector_type(16))) float f32x16;

union BV8 { short8 s; __hip_bfloat16 h[8]; unsigned short u[8]; };
union U32x4 { uint32_t u[4]; short8 s8; };

#define GLD16(gp, lp) \
  __builtin_amdgcn_global_load_lds((const __attribute__((address_space(1))) void*)(gp), \
                                   (__attribute__((address_space(3))) void*)(lp), 16, 0, 0)

// pack two f32 -> bf16 pair (lo = first arg), pure IR (hazard-safe feed into MFMA)
__device__ inline uint32_t pkbf(float a, float b) {
  union { __hip_bfloat16 h; unsigned short u; } ua, ub;
  ua.h = __float2bfloat16(a);
  ub.h = __float2bfloat16(b);
  return ((uint32_t)ub.u << 16) | (uint32_t)ua.u;
}

// ---------------- fp32 -> bf16 convert ----------------
__global__ __launch_bounds__(256) void cvt_f32_bf16(const float* __restrict__ in,
                                                    __hip_bfloat16* __restrict__ out,
                                                    int n4) {
  int i = blockIdx.x * 256 + threadIdx.x;
  if (i >= n4) return;
  float4 v = reinterpret_cast<const float4*>(in)[i];
  BV8 o;
  o.h[0] = __float2bfloat16(v.x);
  o.h[1] = __float2bfloat16(v.y);
  o.h[2] = __float2bfloat16(v.z);
  o.h[3] = __float2bfloat16(v.w);
  ushort4 st = { o.u[0], o.u[1], o.u[2], o.u[3] };
  reinterpret_cast<ushort4*>(out)[i] = st;
}

// ---------------- RoPE cos/sin table: tab[t*32 + i] = {cos(t*inv_i), sin(t*inv_i)} ----------------
// sincosf is a real call here, but nothing is live across it -> no spill.
__global__ __launch_bounds__(256) void rope_cs(float2* __restrict__ tab) {
  int idx = blockIdx.x * 256 + threadIdx.x;  // 65536 entries
  int t = idx >> 5, i = idx & 31;
  float inv = exp2f(-13.287712379549449f * ((float)(2 * i) * (1.0f / 64.0f)));
  float sn, cn;
  sincosf((float)t * inv, &sn, &cn);
  tab[idx] = make_float2(cn, sn);
}

// ---------------- bf16 GEMM, C = A[M,K] * Bt[N,K]^T (XCD-swizzled blocks) ----------------
template <typename OutT>
__global__ __launch_bounds__(256) void gemm_bt(const __hip_bfloat16* __restrict__ A,
                                               const __hip_bfloat16* __restrict__ Bt,
                                               OutT* __restrict__ C,
                                               int M, int N, int K) {
  __shared__ __align__(16) __hip_bfloat16 As[128 * 32];
  __shared__ __align__(16) __hip_bfloat16 Bs[128 * 32];
  const int tid = threadIdx.x;
  const int w = tid >> 6, l = tid & 63;
  const int l15 = l & 15, l4 = l >> 4;
  const int wr = w >> 1, wc = w & 1;
  // T1: bijective XCD chunking (requires nwg % 8 == 0)
  const int gx = (int)gridDim.x;
  const int nwg = gx * (int)gridDim.y;
  int lin = (int)blockIdx.y * gx + (int)blockIdx.x;
  lin = (lin & 7) * (nwg >> 3) + (lin >> 3);
  const long bm = (long)(lin / gx) * 128;
  const long bn = (long)(lin % gx) * 128;

  f32x4 acc[4][4] = {};

  const int srow = tid >> 2;
  const int scol = (tid & 3) * 16;
  char* AsB = (char*)As;
  char* BsB = (char*)Bs;
  const char* Ab  = (const char*)A;
  const char* Btb = (const char*)Bt;

  for (int kt = 0; kt < K; kt += 32) {
    __syncthreads();
#pragma unroll
    for (int it = 0; it < 2; ++it) {
      long arow = bm + it * 64 + srow;
      GLD16(Ab + (arow * K + kt) * 2 + scol, AsB + it * 4096 + w * 1024);
      long brow = bn + it * 64 + srow;
      GLD16(Btb + (brow * K + kt) * 2 + scol, BsB + it * 4096 + w * 1024);
    }
    __syncthreads();
    short8 aF[4], bF[4];
#pragma unroll
    for (int m = 0; m < 4; ++m)
      aF[m] = *(const short8*)(AsB + (wr * 64 + m * 16 + l15) * 64 + l4 * 16);
#pragma unroll
    for (int n = 0; n < 4; ++n)
      bF[n] = *(const short8*)(BsB + (wc * 64 + n * 16 + l15) * 64 + l4 * 16);
#pragma unroll
    for (int m = 0; m < 4; ++m)
#pragma unroll
      for (int n = 0; n < 4; ++n)
        acc[m][n] = __builtin_amdgcn_mfma_f32_16x16x32_bf16(aF[m], bF[n], acc[m][n], 0, 0, 0);
  }

#pragma unroll
  for (int m = 0; m < 4; ++m)
#pragma unroll
    for (int n = 0; n < 4; ++n)
#pragma unroll
      for (int r = 0; r < 4; ++r) {
        long row = bm + wr * 64 + m * 16 + l4 * 4 + r;
        long col = bn + wc * 64 + n * 16 + l15;
        float v = acc[m][n][r];
        if constexpr (sizeof(OutT) == 2) {
          C[row * N + col] = __float2bfloat16(v);
        } else {
          C[row * N + col] = v;
        }
      }
}

// ---------------- fused qkv GEMM + RoPE epilogue (table-driven, no libcalls) ----------------
// C = xb[4096,1024] @ wqkvb[3072,1024]^T. Region by bn: [0,1024)=Q, [1024,2048)=K, else V.
// Q/K: RoPE via cos/sin TABLE lookups (pure loads; nothing forces acc to spill);
// pair exchange via shfl_xor(acc,1). Q folds 0.125*log2e. V -> Vtmp (v_pack transposes).
__global__ __launch_bounds__(256) void gemm_qkv_rope(const __hip_bfloat16* __restrict__ A,
                                                     const __hip_bfloat16* __restrict__ Bt,
                                                     const float2* __restrict__ tab,
                                                     __hip_bfloat16* __restrict__ Qb,
                                                     __hip_bfloat16* __restrict__ Kb,
                                                     __hip_bfloat16* __restrict__ Vtmp) {
  __shared__ __align__(16) __hip_bfloat16 As[128 * 32];
  __shared__ __align__(16) __hip_bfloat16 Bs[128 * 32];
  const int tid = threadIdx.x;
  const int w = tid >> 6, l = tid & 63;
  const int l15 = l & 15, l4 = l >> 4;
  const int wr = w >> 1, wc = w & 1;
  // T1: 768 blocks (24 x 32), chunk 96 per XCD
  int lin = (int)blockIdx.y * 24 + (int)blockIdx.x;
  lin = (lin & 7) * 96 + (lin >> 3);
  const long bm = (long)(lin / 24) * 128;
  const long bn = (long)(lin % 24) * 128;

  f32x4 acc[4][4] = {};

  const int srow = tid >> 2;
  const int scol = (tid & 3) * 16;
  char* AsB = (char*)As;
  char* BsB = (char*)Bs;
  const char* Ab  = (const char*)A;
  const char* Btb = (const char*)Bt;

  for (int kt = 0; kt < 1024; kt += 32) {
    __syncthreads();
#pragma unroll
    for (int it = 0; it < 2; ++it) {
      long arow = bm + it * 64 + srow;
      GLD16(Ab + (arow * 1024 + kt) * 2 + scol, AsB + it * 4096 + w * 1024);
      long brow = bn + it * 64 + srow;
      GLD16(Btb + (brow * 1024 + kt) * 2 + scol, BsB + it * 4096 + w * 1024);
    }
    __syncthreads();
    short8 aF[4], bF[4];
#pragma unroll
    for (int m = 0; m < 4; ++m)
      aF[m] = *(const short8*)(AsB + (wr * 64 + m * 16 + l15) * 64 + l4 * 16);
#pragma unroll
    for (int n = 0; n < 4; ++n)
      bF[n] = *(const short8*)(BsB + (wc * 64 + n * 16 + l15) * 64 + l4 * 16);
#pragma unroll
    for (int m = 0; m < 4; ++m)
#pragma unroll
      for (int n = 0; n < 4; ++n)
        acc[m][n] = __builtin_amdgcn_mfma_f32_16x16x32_bf16(aF[m], bF[n], acc[m][n], 0, 0, 0);
  }

  const int region = (int)(bn >> 10);  // 0=Q 1=K 2=V (block-uniform)
  if (region < 2) {
    __hip_bfloat16* dst = region ? Kb : Qb;
    const float qs = region ? 1.0f : 0.125f * 1.4426950408889634f;
    const int h = ((int)(bn & 1023) >> 6) + wc;  // head (block/wave-uniform)
#pragma unroll
    for (int n = 0; n < 4; ++n) {
      const int d = n * 16 + l15;  // 0..63 within head
      const int i = d >> 1;        // pair index (shared by both pair-lanes)
#pragma unroll
      for (int m = 0; m < 4; ++m) {
#pragma unroll
        for (int r = 0; r < 4; ++r) {
          const int tg = (int)bm + wr * 64 + m * 16 + l4 * 4 + r;
          const int b = tg >> 11, t = tg & 2047;
          const float2 cs = tab[(t << 5) + i];
          const float x = acc[m][n][r];
          const float px = __shfl_xor(x, 1);  // pair partner (same angle)
          const float o = ((l15 & 1) ? (px * cs.y + x * cs.x) : (x * cs.x - px * cs.y)) * qs;
          dst[((size_t)(((b << 4) + h) * 2048 + t)) * 64 + d] = __float2bfloat16(o);
        }
      }
    }
  } else {
    const int colv = (int)(bn & 1023) + wc * 64;
#pragma unroll
    for (int m = 0; m < 4; ++m)
#pragma unroll
      for (int n = 0; n < 4; ++n)
#pragma unroll
        for (int r = 0; r < 4; ++r) {
          const int tg = (int)bm + wr * 64 + m * 16 + l4 * 4 + r;
          Vtmp[(size_t)tg * 1024 + colv + n * 16 + l15] = __float2bfloat16(acc[m][n][r]);
        }
  }
}

// ---------------- V transpose: Vtmp[b*2048+t][h*64+d] -> VTb[bh][d][t] ----------------
__global__ __launch_bounds__(256) void v_pack(const __hip_bfloat16* __restrict__ Vtmp,
                                              __hip_bfloat16* __restrict__ VTb) {
  __shared__ __hip_bfloat16 vt[64][72];
  const int bh = blockIdx.x;
  const int b = bh >> 4, h = bh & 15;
  const int t0 = blockIdx.y * 64;
  const int tid = threadIdx.x;

#pragma unroll
  for (int rep = 0; rep < 2; ++rep) {
    int idx = rep * 256 + tid;
    int tt = idx >> 3;
    int d0 = (idx & 7) * 8;
    int t = t0 + tt;
    BV8 vv;
    vv.s = *(const short8*)(Vtmp + ((size_t)(b * T_CTX + t)) * 1024 + h * 64 + d0);
#pragma unroll
    for (int j = 0; j < 8; ++j) vt[d0 + j][tt] = vv.h[j];
  }
  __syncthreads();
#pragma unroll
  for (int rep = 0; rep < 2; ++rep) {
    int idx = rep * 256 + tid;
    int d = idx >> 3;
    int toff = (idx & 7) * 8;
    BV8 o;
#pragma unroll
    for (int j = 0; j < 8; ++j) o.h[j] = vt[d][toff + j];
    *(short8*)(VTb + ((size_t)bh * 64 + d) * T_CTX + t0 + toff) = o.s;
  }
}

// ---------------- flash attention (causal), 32x32 MFMA, paired-tile barriers ----------------
// (unchanged from round 12: 4 waves = qsub x kh, 64-row balanced slab pairs, k-split,
// fixed-base exp2 softmax, end-of-kernel merge, two KV tiles per barrier)
__global__ __launch_bounds__(256) void flash_attn(const __hip_bfloat16* __restrict__ Qb,
                                                  const __hip_bfloat16* __restrict__ Kb,
                                                  const __hip_bfloat16* __restrict__ VTb,
                                                  __hip_bfloat16* __restrict__ Y) {
  __shared__ __align__(16) char smem[65536];
  const int bh = blockIdx.x;
  const int b = bh >> 4, h = bh & 15;
  const int y = blockIdx.y;
  const int jA = 31 - y;
  const int jB = y;
  const int tid = threadIdx.x;
  const int w = tid >> 6, l = tid & 63;
  const int qsub = w >> 1, kh = w & 1;
  const int l31 = l & 31, hh = l >> 5;
  const int sw7 = (l31 & 7) << 4;
  const int rowb = tid >> 3;
  const int colS = (tid & 7) * 16;

#define STAGE1(gg)                                                                     \
  {                                                                                    \
    const int tt_ = ((gg) <= jA) ? (gg) : (gg) - jA - 1;                               \
    const int kv0_ = tt_ << 6;                                                         \
    char* base_ = smem + (((gg) >> 1) & 1) * 32768 + ((gg) & 1) * 16384;               \
    _Pragma("unroll")                                                                  \
    for (int rnd = 0; rnd < 2; ++rnd) {                                                \
      int row = rnd * 32 + rowb;                                                       \
      int sw = colS ^ ((row & 7) << 4);                                                \
      GLD16((const char*)Kb + (((size_t)bh * T_CTX + kv0_ + row) << 7) + sw,           \
            base_ + rnd * 4096 + w * 1024);                                            \
      GLD16((const char*)VTb + ((((size_t)bh * 64 + row) * T_CTX + kv0_) << 1) + sw,   \
            base_ + 8192 + rnd * 4096 + w * 1024);                                     \
    }                                                                                  \
  }

  f32x16 oA0 = {}, oA1 = {}, oB0 = {}, oB1 = {};
  float lrA = 0.0f, lrB = 0.0f;

  STAGE1(0)
  STAGE1(1)

  int rr = 0;
#pragma unroll
  for (int ph = 0; ph < 2; ++ph) {
    const int j = ph ? jB : jA;
    const int qglob = j * 64 + qsub * 32 + l31;
    f32x16& od0 = ph ? oB0 : oA0;
    f32x16& od1 = ph ? oB1 : oA1;
    float& lrw = ph ? lrB : lrA;

    short8 qB[4];
#pragma unroll
    for (int dblk = 0; dblk < 4; ++dblk)
      qB[dblk] = *(const short8*)(Qb + ((size_t)bh * T_CTX + qglob) * 64 + dblk * 16 + hh * 8);

    for (int t = 0; t <= j; ++t, ++rr) {
      if ((rr & 1) == 0) {
        __syncthreads();
        if (rr + 2 <= 32) STAGE1(rr + 2)
        if (rr + 3 <= 32) STAGE1(rr + 3)
      }
      const char* KsB = smem + ((rr >> 1) & 1) * 32768 + (rr & 1) * 16384;
      const char* VsB = KsB + 8192;
      const int kv0 = t << 6;
      const bool lastT = (t == j);

      if (!(lastT && kh > qsub)) {
        short8 kA[4];
#pragma unroll
        for (int dblk = 0; dblk < 4; ++dblk)
          kA[dblk] = *(const short8*)(KsB + (kh * 32 + l31) * 128 + ((dblk * 32 + hh * 16) ^ sw7));
        short8 vA[2][2];
#pragma unroll
        for (int dt = 0; dt < 2; ++dt)
#pragma unroll
          for (int ks = 0; ks < 2; ++ks)
            vA[dt][ks] = *(const short8*)(VsB + (dt * 32 + l31) * 128 +
                                          ((kh * 64 + ks * 32 + hh * 16) ^ sw7));

        f32x16 sT = {};
#pragma unroll
        for (int dblk = 0; dblk < 4; ++dblk) {
          __builtin_amdgcn_s_setprio(1);
          sT = __builtin_amdgcn_mfma_f32_32x32x16_bf16(kA[dblk], qB[dblk], sT, 0, 0, 0);
          __builtin_amdgcn_s_setprio(0);
        }
        if (lastT && kh == qsub) {
          const int kbase = kv0 + kh * 32 + 4 * hh;
#pragma unroll
          for (int r = 0; r < 16; ++r) {
            int kg = kbase + (r & 3) + 8 * (r >> 2);
            sT[r] = (kg > qglob) ? -1e30f : sT[r];
          }
        }
        float s8[8];
#pragma unroll
        for (int i = 0; i < 8; ++i) {
          sT[i]     = __builtin_amdgcn_exp2f(sT[i]);
          sT[i + 8] = __builtin_amdgcn_exp2f(sT[i + 8]);
          s8[i] = sT[i] + sT[i + 8];
        }
        float ps = ((s8[0] + s8[1]) + (s8[2] + s8[3])) + ((s8[4] + s8[5]) + (s8[6] + s8[7]));
        ps += __shfl_xor(ps, 32);
        lrw += ps;
        uint32_t wk[8];
#pragma unroll
        for (int i = 0; i < 8; ++i) wk[i] = pkbf(sT[2 * i], sT[2 * i + 1]);
#pragma unroll
        for (int ks = 0; ks < 2; ++ks) {
          const int base = ks * 4;
          uint32_t own0 = wk[base + 0], own1 = wk[base + 1];
          uint32_t own2 = wk[base + 2], own3 = wk[base + 3];
          uint32_t e0 = (uint32_t)__shfl_xor((int)(hh ? own0 : own2), 32);
          uint32_t e1 = (uint32_t)__shfl_xor((int)(hh ? own1 : own3), 32);
          U32x4 u;
          u.u[0] = hh ? e0 : own0;
          u.u[1] = hh ? e1 : own1;
          u.u[2] = hh ? own2 : e0;
          u.u[3] = hh ? own3 : e1;
          __builtin_amdgcn_s_setprio(1);
          od0 = __builtin_amdgcn_mfma_f32_32x32x16_bf16(vA[0][ks], u.s8, od0, 0, 0, 0);
          od1 = __builtin_amdgcn_mfma_f32_32x32x16_bf16(vA[1][ks], u.s8, od1, 0, 0, 0);
          __builtin_amdgcn_s_setprio(0);
        }
      }
    }
  }

  __syncthreads();
  {
    float* exch = (float*)smem;
    float* lst = exch + 8192;
    const int slotA = (0 * 2 + qsub) * 2 + kh;
    const int slotB = (1 * 2 + qsub) * 2 + kh;
    const f32x16& nA = kh ? oA0 : oA1;
    const f32x16& nB = kh ? oB0 : oB1;
#pragma unroll
    for (int m = 0; m < 4; ++m) {
      int c = ((2 * m + hh) ^ (l31 & 7)) * 4;
      f32x4 va, vb;
#pragma unroll
      for (int i = 0; i < 4; ++i) { va[i] = nA[m * 4 + i]; vb[i] = nB[m * 4 + i]; }
      *(f32x4*)(exch + slotA * 1024 + l31 * 32 + c) = va;
      *(f32x4*)(exch + slotB * 1024 + l31 * 32 + c) = vb;
    }
    if (hh == 0) {
      lst[slotA * 32 + l31] = lrA;
      lst[slotB * 32 + l31] = lrB;
    }
    __syncthreads();
    const int pA = (0 * 2 + qsub) * 2 + (kh ^ 1);
    const int pB = (1 * 2 + qsub) * 2 + (kh ^ 1);
    float ltA = lrA + lst[pA * 32 + l31];
    float ltB = lrB + lst[pB * 32 + l31];
    f32x16& ownA = kh ? oA1 : oA0;
    f32x16& ownB = kh ? oB1 : oB0;
#pragma unroll
    for (int m = 0; m < 4; ++m) {
      int c = ((2 * m + hh) ^ (l31 & 7)) * 4;
      f32x4 aA = *(const f32x4*)(exch + pA * 1024 + l31 * 32 + c);
      f32x4 aB = *(const f32x4*)(exch + pB * 1024 + l31 * 32 + c);
#pragma unroll
      for (int i = 0; i < 4; ++i) { ownA[m * 4 + i] += aA[i]; ownB[m * 4 + i] += aB[i]; }
    }
#pragma unroll
    for (int sl = 0; sl < 2; ++sl) {
      const f32x16& ov = sl ? ownB : ownA;
      float inv = 1.0f / (sl ? ltB : ltA);
      int q0s = (sl ? jB : jA) * 64 + qsub * 32;
      size_t rowoff = ((size_t)(b * T_CTX + q0s + l31)) * DIM_C + h * 64 + kh * 32;
#pragma unroll
      for (int m = 0; m < 4; ++m) {
        union { ushort4 v; unsigned short us[4]; } st;
#pragma unroll
        for (int i = 0; i < 4; ++i) {
          union { __hip_bfloat16 h2; unsigned short u; } cv;
          cv.h2 = __float2bfloat16(ov[m * 4 + i] * inv);
          st.us[i] = cv.u;
        }
        *(ushort4*)(Y + rowoff + 8 * m + 4 * hh) = st.v;
      }
    }
  }
#undef STAGE1
}

// ---------------- launcher ----------------
extern "C" void kernel_launch(void* const* d_in, const int* in_sizes, int n_in,
                              void* d_out, int out_size, void* d_ws, size_t ws_size,
                              hipStream_t stream) {
  const float* x     = (const float*)d_in[0];
  const float* qkv_w = (const float*)d_in[1];
  const float* out_w = (const float*)d_in[2];
  float* out = (float*)d_out;

  char* ws = (char*)d_ws;
  const size_t MB = 1024 * 1024;
  __hip_bfloat16* xb    = (__hip_bfloat16*)(ws + 0 * MB);
  __hip_bfloat16* wqkvb = (__hip_bfloat16*)(ws + 8 * MB);
  __hip_bfloat16* woutb = (__hip_bfloat16*)(ws + 14 * MB);
  __hip_bfloat16* Vtmp  = (__hip_bfloat16*)(ws + 16 * MB);  // 4096x1024 bf16 = 8MB
  float2*         tab   = (float2*)(ws + 32 * MB);          // 65536 float2 = 512KB
  __hip_bfloat16* Qb    = (__hip_bfloat16*)(ws + 40 * MB);
  __hip_bfloat16* Kb    = (__hip_bfloat16*)(ws + 48 * MB);
  __hip_bfloat16* VTb   = (__hip_bfloat16*)(ws + 56 * MB);
  __hip_bfloat16* yb    = (__hip_bfloat16*)(ws + 64 * MB);

  cvt_f32_bf16<<<4096, 256, 0, stream>>>(x, xb, 1048576);
  cvt_f32_bf16<<<3072, 256, 0, stream>>>(qkv_w, wqkvb, 786432);
  cvt_f32_bf16<<<1024, 256, 0, stream>>>(out_w, woutb, 262144);
  rope_cs<<<256, 256, 0, stream>>>(tab);

  // fused qkv GEMM + RoPE (table-driven): writes Qb/Kb directly; V to Vtmp
  gemm_qkv_rope<<<dim3(24, 32), 256, 0, stream>>>(xb, wqkvb, tab, Qb, Kb, Vtmp);

  // V transpose only (16MB traffic vs rope_pack's 48MB)
  v_pack<<<dim3(NBH, 32), 256, 0, stream>>>(Vtmp, VTb);

  // 16 slab-pairs (31-y, y of 64-row slabs) x 32 bh = 512 blocks, 4 waves each
  flash_attn<<<dim3(NBH, 16), 256, 0, stream>>>(Qb, Kb, VTb, yb);

  gemm_bt<float><<<dim3(8, 32), 256, 0, stream>>>(yb, woutb, out, 4096, 1024, 1024);
}

// Round 15
// 114.180 us; speedup vs baseline: 5.1733x; 1.2303x over previous
//
#include <hip/hip_runtime.h>
#include <hip/hip_bf16.h>
#include <cstdint>
#include <cstddef>

#define B_SZ   2
#define T_CTX  2048
#define DIM_C  1024
#define NHEAD  16
#define HD     64
#define NBH    (B_SZ*NHEAD)

typedef __attribute__((ext_vector_type(8))) short short8;
typedef __attribute__((ext_vector_type(4))) float f32x4;
typedef __attribute__((ext_vector_type(16))) float f32x16;

union BV8 { short8 s; __hip_bfloat16 h[8]; unsigned short u[8]; };
union U32x4 { uint32_t u[4]; short8 s8; };

#define GLD16(gp, lp) \
  __builtin_amdgcn_global_load_lds((const __attribute__((address_space(1))) void*)(gp), \
                                   (__attribute__((address_space(3))) void*)(lp), 16, 0, 0)

// pack two f32 -> bf16 pair (lo = first arg), pure IR (hazard-safe feed into MFMA)
__device__ inline uint32_t pkbf(float a, float b) {
  union { __hip_bfloat16 h; unsigned short u; } ua, ub;
  ua.h = __float2bfloat16(a);
  ub.h = __float2bfloat16(b);
  return ((uint32_t)ub.u << 16) | (uint32_t)ua.u;
}

// ---------------- fp32 -> bf16 convert, all three inputs in one launch ----------------
// exact: 1048576 + 786432 + 262144 = 2097152 float4 = 8192 blocks x 256
__global__ __launch_bounds__(256) void cvt_all(const float* __restrict__ x,
                                               const float* __restrict__ wq,
                                               const float* __restrict__ wo,
                                               __hip_bfloat16* __restrict__ xb,
                                               __hip_bfloat16* __restrict__ wqb,
                                               __hip_bfloat16* __restrict__ wob) {
  int i = blockIdx.x * 256 + threadIdx.x;
  const float* src;
  __hip_bfloat16* dst;
  int off;
  if (i < 1048576) { src = x; dst = xb; off = i; }
  else if (i < 1835008) { src = wq; dst = wqb; off = i - 1048576; }
  else { src = wo; dst = wob; off = i - 1835008; }
  float4 v = reinterpret_cast<const float4*>(src)[off];
  BV8 o;
  o.h[0] = __float2bfloat16(v.x);
  o.h[1] = __float2bfloat16(v.y);
  o.h[2] = __float2bfloat16(v.z);
  o.h[3] = __float2bfloat16(v.w);
  ushort4 st = { o.u[0], o.u[1], o.u[2], o.u[3] };
  reinterpret_cast<ushort4*>(dst)[off] = st;
}

// ---------------- bf16 GEMM, C = A[M,K] * Bt[N,K]^T ----------------
// BK=64 (half the barriers of BK=32). 128B LDS rows staged with pre-swizzled
// global source (scol ^ ((row&7)<<4)), linear global_load_lds dest, same XOR on
// ds_read_b128 -> conflict-free (flash-proven pattern). T1 XCD chunking.
template <typename OutT>
__global__ __launch_bounds__(256) void gemm_bt(const __hip_bfloat16* __restrict__ A,
                                               const __hip_bfloat16* __restrict__ Bt,
                                               OutT* __restrict__ C,
                                               int M, int N, int K) {
  __shared__ __align__(16) __hip_bfloat16 As[128 * 64];
  __shared__ __align__(16) __hip_bfloat16 Bs[128 * 64];
  const int tid = threadIdx.x;
  const int w = tid >> 6, l = tid & 63;
  const int l15 = l & 15, l4 = l >> 4;
  const int wr = w >> 1, wc = w & 1;
  // T1: bijective XCD chunking (requires nwg % 8 == 0)
  const int gx = (int)gridDim.x;
  const int nwg = gx * (int)gridDim.y;
  int lin = (int)blockIdx.y * gx + (int)blockIdx.x;
  lin = (lin & 7) * (nwg >> 3) + (lin >> 3);
  const long bm = (long)(lin / gx) * 128;
  const long bn = (long)(lin % gx) * 128;

  f32x4 acc[4][4] = {};

  const int srow = tid >> 3;            // 0..31 (row within 32-row staging group)
  const int scol = (tid & 7) * 16;      // byte col within 128B row
  const int ssw  = scol ^ ((srow & 7) << 4);  // pre-swizzled source column
  char* AsB = (char*)As;
  char* BsB = (char*)Bs;
  const char* Ab  = (const char*)A;
  const char* Btb = (const char*)Bt;

  for (int kt = 0; kt < K; kt += 64) {
    __syncthreads();
#pragma unroll
    for (int it = 0; it < 4; ++it) {
      long arow = bm + it * 32 + srow;
      GLD16(Ab + (arow * K + kt) * 2 + ssw, AsB + it * 4096 + w * 1024);
      long brow = bn + it * 32 + srow;
      GLD16(Btb + (brow * K + kt) * 2 + ssw, BsB + it * 4096 + w * 1024);
    }
    __syncthreads();
#pragma unroll
    for (int ksub = 0; ksub < 2; ++ksub) {
      short8 aF[4], bF[4];
#pragma unroll
      for (int m = 0; m < 4; ++m) {
        int R = wr * 64 + m * 16 + l15;
        aF[m] = *(const short8*)(AsB + R * 128 + ((ksub * 64 + l4 * 16) ^ ((R & 7) << 4)));
      }
#pragma unroll
      for (int n = 0; n < 4; ++n) {
        int R = wc * 64 + n * 16 + l15;
        bF[n] = *(const short8*)(BsB + R * 128 + ((ksub * 64 + l4 * 16) ^ ((R & 7) << 4)));
      }
#pragma unroll
      for (int m = 0; m < 4; ++m)
#pragma unroll
        for (int n = 0; n < 4; ++n)
          acc[m][n] = __builtin_amdgcn_mfma_f32_16x16x32_bf16(aF[m], bF[n], acc[m][n], 0, 0, 0);
    }
  }

#pragma unroll
  for (int m = 0; m < 4; ++m)
#pragma unroll
    for (int n = 0; n < 4; ++n)
#pragma unroll
      for (int r = 0; r < 4; ++r) {
        long row = bm + wr * 64 + m * 16 + l4 * 4 + r;
        long col = bn + wc * 64 + n * 16 + l15;
        float v = acc[m][n][r];
        if constexpr (sizeof(OutT) == 2) {
          C[row * N + col] = __float2bfloat16(v);
        } else {
          C[row * N + col] = v;
        }
      }
}

// ---------------- RoPE + repack (round-12 known-good) ----------------
// Q scale folds softmax 1/8 AND log2(e) so attention softmax can use exp2 natively.
__global__ __launch_bounds__(256) void rope_pack(const __hip_bfloat16* __restrict__ qkv,
                                                 __hip_bfloat16* __restrict__ Qb,
                                                 __hip_bfloat16* __restrict__ Kb,
                                                 __hip_bfloat16* __restrict__ VTb) {
  __shared__ __hip_bfloat16 vt[64][72];
  const int bh = blockIdx.x;
  const int b = bh >> 4, h = bh & 15;
  const int t0 = blockIdx.y * 64;
  const int tid = threadIdx.x;
  const float QSCL = 0.125f * 1.4426950408889634f;

#pragma unroll
  for (int rep = 0; rep < 2; ++rep) {
    int idx = rep * 256 + tid;
    int tt = idx >> 3;
    int d0 = (idx & 7) * 8;
    int t = t0 + tt;
    size_t src = ((size_t)(b * T_CTX + t)) * 3072 + h * 64 + d0;
    BV8 qv, kv, vv, qo, ko;
    qv.s = *(const short8*)(qkv + src);
    kv.s = *(const short8*)(qkv + src + 1024);
    vv.s = *(const short8*)(qkv + src + 2048);
#pragma unroll
    for (int p = 0; p < 4; ++p) {
      int i = (d0 >> 1) + p;
      float inv = exp2f(-13.287712379549449f * ((float)(2 * i) * (1.0f / 64.0f)));
      float ang = (float)t * inv;
      float sn, cn;
      sincosf(ang, &sn, &cn);
      float q1 = __bfloat162float(qv.h[2 * p]);
      float q2 = __bfloat162float(qv.h[2 * p + 1]);
      float k1 = __bfloat162float(kv.h[2 * p]);
      float k2 = __bfloat162float(kv.h[2 * p + 1]);
      qo.h[2 * p]     = __float2bfloat16((q1 * cn - q2 * sn) * QSCL);
      qo.h[2 * p + 1] = __float2bfloat16((q1 * sn + q2 * cn) * QSCL);
      ko.h[2 * p]     = __float2bfloat16(k1 * cn - k2 * sn);
      ko.h[2 * p + 1] = __float2bfloat16(k1 * sn + k2 * cn);
    }
    size_t dst = ((size_t)bh * T_CTX + t) * 64 + d0;
    *(short8*)(Qb + dst) = qo.s;
    *(short8*)(Kb + dst) = ko.s;
#pragma unroll
    for (int j = 0; j < 8; ++j) vt[d0 + j][tt] = vv.h[j];
  }
  __syncthreads();
#pragma unroll
  for (int rep = 0; rep < 2; ++rep) {
    int idx = rep * 256 + tid;
    int d = idx >> 3;
    int toff = (idx & 7) * 8;
    BV8 o;
#pragma unroll
    for (int j = 0; j < 8; ++j) o.h[j] = vt[d][toff + j];
    *(short8*)(VTb + ((size_t)bh * 64 + d) * T_CTX + t0 + toff) = o.s;
  }
}

// ---------------- flash attention (causal), 32x32 MFMA, paired-tile barriers ----------------
// (round-12 known-good: 4 waves = qsub x kh, 64-row balanced slab pairs, k-split,
// fixed-base exp2 softmax, end-of-kernel merge, two KV tiles per barrier)
__global__ __launch_bounds__(256) void flash_attn(const __hip_bfloat16* __restrict__ Qb,
                                                  const __hip_bfloat16* __restrict__ Kb,
                                                  const __hip_bfloat16* __restrict__ VTb,
                                                  __hip_bfloat16* __restrict__ Y) {
  __shared__ __align__(16) char smem[65536];
  const int bh = blockIdx.x;
  const int b = bh >> 4, h = bh & 15;
  const int y = blockIdx.y;
  const int jA = 31 - y;
  const int jB = y;
  const int tid = threadIdx.x;
  const int w = tid >> 6, l = tid & 63;
  const int qsub = w >> 1, kh = w & 1;
  const int l31 = l & 31, hh = l >> 5;
  const int sw7 = (l31 & 7) << 4;
  const int rowb = tid >> 3;
  const int colS = (tid & 7) * 16;

#define STAGE1(gg)                                                                     \
  {                                                                                    \
    const int tt_ = ((gg) <= jA) ? (gg) : (gg) - jA - 1;                               \
    const int kv0_ = tt_ << 6;                                                         \
    char* base_ = smem + (((gg) >> 1) & 1) * 32768 + ((gg) & 1) * 16384;               \
    _Pragma("unroll")                                                                  \
    for (int rnd = 0; rnd < 2; ++rnd) {                                                \
      int row = rnd * 32 + rowb;                                                       \
      int sw = colS ^ ((row & 7) << 4);                                                \
      GLD16((const char*)Kb + (((size_t)bh * T_CTX + kv0_ + row) << 7) + sw,           \
            base_ + rnd * 4096 + w * 1024);                                            \
      GLD16((const char*)VTb + ((((size_t)bh * 64 + row) * T_CTX + kv0_) << 1) + sw,   \
            base_ + 8192 + rnd * 4096 + w * 1024);                                     \
    }                                                                                  \
  }

  f32x16 oA0 = {}, oA1 = {}, oB0 = {}, oB1 = {};
  float lrA = 0.0f, lrB = 0.0f;

  STAGE1(0)
  STAGE1(1)

  int rr = 0;
#pragma unroll
  for (int ph = 0; ph < 2; ++ph) {
    const int j = ph ? jB : jA;
    const int qglob = j * 64 + qsub * 32 + l31;
    f32x16& od0 = ph ? oB0 : oA0;
    f32x16& od1 = ph ? oB1 : oA1;
    float& lrw = ph ? lrB : lrA;

    short8 qB[4];
#pragma unroll
    for (int dblk = 0; dblk < 4; ++dblk)
      qB[dblk] = *(const short8*)(Qb + ((size_t)bh * T_CTX + qglob) * 64 + dblk * 16 + hh * 8);

    for (int t = 0; t <= j; ++t, ++rr) {
      if ((rr & 1) == 0) {
        __syncthreads();
        if (rr + 2 <= 32) STAGE1(rr + 2)
        if (rr + 3 <= 32) STAGE1(rr + 3)
      }
      const char* KsB = smem + ((rr >> 1) & 1) * 32768 + (rr & 1) * 16384;
      const char* VsB = KsB + 8192;
      const int kv0 = t << 6;
      const bool lastT = (t == j);

      if (!(lastT && kh > qsub)) {
        short8 kA[4];
#pragma unroll
        for (int dblk = 0; dblk < 4; ++dblk)
          kA[dblk] = *(const short8*)(KsB + (kh * 32 + l31) * 128 + ((dblk * 32 + hh * 16) ^ sw7));
        short8 vA[2][2];
#pragma unroll
        for (int dt = 0; dt < 2; ++dt)
#pragma unroll
          for (int ks = 0; ks < 2; ++ks)
            vA[dt][ks] = *(const short8*)(VsB + (dt * 32 + l31) * 128 +
                                          ((kh * 64 + ks * 32 + hh * 16) ^ sw7));

        f32x16 sT = {};
#pragma unroll
        for (int dblk = 0; dblk < 4; ++dblk) {
          __builtin_amdgcn_s_setprio(1);
          sT = __builtin_amdgcn_mfma_f32_32x32x16_bf16(kA[dblk], qB[dblk], sT, 0, 0, 0);
          __builtin_amdgcn_s_setprio(0);
        }
        if (lastT && kh == qsub) {
          const int kbase = kv0 + kh * 32 + 4 * hh;
#pragma unroll
          for (int r = 0; r < 16; ++r) {
            int kg = kbase + (r & 3) + 8 * (r >> 2);
            sT[r] = (kg > qglob) ? -1e30f : sT[r];
          }
        }
        float s8[8];
#pragma unroll
        for (int i = 0; i < 8; ++i) {
          sT[i]     = __builtin_amdgcn_exp2f(sT[i]);
          sT[i + 8] = __builtin_amdgcn_exp2f(sT[i + 8]);
          s8[i] = sT[i] + sT[i + 8];
        }
        float ps = ((s8[0] + s8[1]) + (s8[2] + s8[3])) + ((s8[4] + s8[5]) + (s8[6] + s8[7]));
        ps += __shfl_xor(ps, 32);
        lrw += ps;
        uint32_t wk[8];
#pragma unroll
        for (int i = 0; i < 8; ++i) wk[i] = pkbf(sT[2 * i], sT[2 * i + 1]);
#pragma unroll
        for (int ks = 0; ks < 2; ++ks) {
          const int base = ks * 4;
          uint32_t own0 = wk[base + 0], own1 = wk[base + 1];
          uint32_t own2 = wk[base + 2], own3 = wk[base + 3];
          uint32_t e0 = (uint32_t)__shfl_xor((int)(hh ? own0 : own2), 32);
          uint32_t e1 = (uint32_t)__shfl_xor((int)(hh ? own1 : own3), 32);
          U32x4 u;
          u.u[0] = hh ? e0 : own0;
          u.u[1] = hh ? e1 : own1;
          u.u[2] = hh ? own2 : e0;
          u.u[3] = hh ? own3 : e1;
          __builtin_amdgcn_s_setprio(1);
          od0 = __builtin_amdgcn_mfma_f32_32x32x16_bf16(vA[0][ks], u.s8, od0, 0, 0, 0);
          od1 = __builtin_amdgcn_mfma_f32_32x32x16_bf16(vA[1][ks], u.s8, od1, 0, 0, 0);
          __builtin_amdgcn_s_setprio(0);
        }
      }
    }
  }

  __syncthreads();
  {
    float* exch = (float*)smem;
    float* lst = exch + 8192;
    const int slotA = (0 * 2 + qsub) * 2 + kh;
    const int slotB = (1 * 2 + qsub) * 2 + kh;
    const f32x16& nA = kh ? oA0 : oA1;
    const f32x16& nB = kh ? oB0 : oB1;
#pragma unroll
    for (int m = 0; m < 4; ++m) {
      int c = ((2 * m + hh) ^ (l31 & 7)) * 4;
      f32x4 va, vb;
#pragma unroll
      for (int i = 0; i < 4; ++i) { va[i] = nA[m * 4 + i]; vb[i] = nB[m * 4 + i]; }
      *(f32x4*)(exch + slotA * 1024 + l31 * 32 + c) = va;
      *(f32x4*)(exch + slotB * 1024 + l31 * 32 + c) = vb;
    }
    if (hh == 0) {
      lst[slotA * 32 + l31] = lrA;
      lst[slotB * 32 + l31] = lrB;
    }
    __syncthreads();
    const int pA = (0 * 2 + qsub) * 2 + (kh ^ 1);
    const int pB = (1 * 2 + qsub) * 2 + (kh ^ 1);
    float ltA = lrA + lst[pA * 32 + l31];
    float ltB = lrB + lst[pB * 32 + l31];
    f32x16& ownA = kh ? oA1 : oA0;
    f32x16& ownB = kh ? oB1 : oB0;
#pragma unroll
    for (int m = 0; m < 4; ++m) {
      int c = ((2 * m + hh) ^ (l31 & 7)) * 4;
      f32x4 aA = *(const f32x4*)(exch + pA * 1024 + l31 * 32 + c);
      f32x4 aB = *(const f32x4*)(exch + pB * 1024 + l31 * 32 + c);
#pragma unroll
      for (int i = 0; i < 4; ++i) { ownA[m * 4 + i] += aA[i]; ownB[m * 4 + i] += aB[i]; }
    }
#pragma unroll
    for (int sl = 0; sl < 2; ++sl) {
      const f32x16& ov = sl ? ownB : ownA;
      float inv = 1.0f / (sl ? ltB : ltA);
      int q0s = (sl ? jB : jA) * 64 + qsub * 32;
      size_t rowoff = ((size_t)(b * T_CTX + q0s + l31)) * DIM_C + h * 64 + kh * 32;
#pragma unroll
      for (int m = 0; m < 4; ++m) {
        union { ushort4 v; unsigned short us[4]; } st;
#pragma unroll
        for (int i = 0; i < 4; ++i) {
          union { __hip_bfloat16 h2; unsigned short u; } cv;
          cv.h2 = __float2bfloat16(ov[m * 4 + i] * inv);
          st.us[i] = cv.u;
        }
        *(ushort4*)(Y + rowoff + 8 * m + 4 * hh) = st.v;
      }
    }
  }
#undef STAGE1
}

// ---------------- launcher ----------------
extern "C" void kernel_launch(void* const* d_in, const int* in_sizes, int n_in,
                              void* d_out, int out_size, void* d_ws, size_t ws_size,
                              hipStream_t stream) {
  const float* x     = (const float*)d_in[0];
  const float* qkv_w = (const float*)d_in[1];
  const float* out_w = (const float*)d_in[2];
  float* out = (float*)d_out;

  char* ws = (char*)d_ws;
  const size_t MB = 1024 * 1024;
  __hip_bfloat16* xb    = (__hip_bfloat16*)(ws + 0 * MB);
  __hip_bfloat16* wqkvb = (__hip_bfloat16*)(ws + 8 * MB);
  __hip_bfloat16* woutb = (__hip_bfloat16*)(ws + 14 * MB);
  __hip_bfloat16* qkvb  = (__hip_bfloat16*)(ws + 16 * MB);
  __hip_bfloat16* Qb    = (__hip_bfloat16*)(ws + 40 * MB);
  __hip_bfloat16* Kb    = (__hip_bfloat16*)(ws + 48 * MB);
  __hip_bfloat16* VTb   = (__hip_bfloat16*)(ws + 56 * MB);
  __hip_bfloat16* yb    = (__hip_bfloat16*)(ws + 64 * MB);

  // single fused convert launch
  cvt_all<<<8192, 256, 0, stream>>>(x, qkv_w, out_w, xb, wqkvb, woutb);

  // qkv = x @ qkv_w^T (BK=64)
  gemm_bt<__hip_bfloat16><<<dim3(24, 32), 256, 0, stream>>>(xb, wqkvb, qkvb, 4096, 3072, 1024);

  rope_pack<<<dim3(32, 32), 256, 0, stream>>>(qkvb, Qb, Kb, VTb);

  // 16 slab-pairs (31-y, y of 64-row slabs) x 32 bh = 512 blocks, 4 waves each
  flash_attn<<<dim3(NBH, 16), 256, 0, stream>>>(Qb, Kb, VTb, yb);

  // out = y @ out_w^T (BK=64, fp32 out)
  gemm_bt<float><<<dim3(8, 32), 256, 0, stream>>>(yb, woutb, out, 4096, 1024, 1024);
}

// Round 16
// 107.095 us; speedup vs baseline: 5.5156x; 1.0662x over previous
//
#include <hip/hip_runtime.h>
#include <hip/hip_bf16.h>
#include <cstdint>
#include <cstddef>

#define B_SZ   2
#define T_CTX  2048
#define DIM_C  1024
#define NHEAD  16
#define HD     64
#define NBH    (B_SZ*NHEAD)

typedef __attribute__((ext_vector_type(8))) short short8;
typedef __attribute__((ext_vector_type(4))) float f32x4;
typedef __attribute__((ext_vector_type(16))) float f32x16;

union BV8 { short8 s; __hip_bfloat16 h[8]; unsigned short u[8]; };
union U32x4 { uint32_t u[4]; short8 s8; };

#define GLD16(gp, lp) \
  __builtin_amdgcn_global_load_lds((const __attribute__((address_space(1))) void*)(gp), \
                                   (__attribute__((address_space(3))) void*)(lp), 16, 0, 0)

// pack two f32 -> bf16 pair (lo = first arg), pure IR (hazard-safe feed into MFMA)
__device__ inline uint32_t pkbf(float a, float b) {
  union { __hip_bfloat16 h; unsigned short u; } ua, ub;
  ua.h = __float2bfloat16(a);
  ub.h = __float2bfloat16(b);
  return ((uint32_t)ub.u << 16) | (uint32_t)ua.u;
}

// ---------------- fp32 -> bf16 convert, all three inputs in one launch ----------------
__global__ __launch_bounds__(256) void cvt_all(const float* __restrict__ x,
                                               const float* __restrict__ wq,
                                               const float* __restrict__ wo,
                                               __hip_bfloat16* __restrict__ xb,
                                               __hip_bfloat16* __restrict__ wqb,
                                               __hip_bfloat16* __restrict__ wob) {
  int i = blockIdx.x * 256 + threadIdx.x;
  const float* src;
  __hip_bfloat16* dst;
  int off;
  if (i < 1048576) { src = x; dst = xb; off = i; }
  else if (i < 1835008) { src = wq; dst = wqb; off = i - 1048576; }
  else { src = wo; dst = wob; off = i - 1835008; }
  float4 v = reinterpret_cast<const float4*>(src)[off];
  BV8 o;
  o.h[0] = __float2bfloat16(v.x);
  o.h[1] = __float2bfloat16(v.y);
  o.h[2] = __float2bfloat16(v.z);
  o.h[3] = __float2bfloat16(v.w);
  ushort4 st = { o.u[0], o.u[1], o.u[2], o.u[3] };
  reinterpret_cast<ushort4*>(dst)[off] = st;
}

// ---------------- bf16 GEMM, C = A[M,K] * Bt[N,K]^T ----------------
// BK=64, DOUBLE-BUFFERED staging (flash-proven pattern): prologue stages buf0;
// per K-step {barrier; stage next -> buf^1; compute cur}. Staging latency hides
// under compute; 16 barriers/block. 128B LDS rows via pre-swizzled global source
// (scol ^ ((row&7)<<4)), linear global_load_lds dest, same XOR on ds_read_b128.
// T1 XCD chunking.
template <typename OutT>
__global__ __launch_bounds__(256) void gemm_bt(const __hip_bfloat16* __restrict__ A,
                                               const __hip_bfloat16* __restrict__ Bt,
                                               OutT* __restrict__ C,
                                               int M, int N, int K) {
  __shared__ __align__(16) char smem[65536];  // buf b at b*32768: A 16KB, B 16KB
  const int tid = threadIdx.x;
  const int w = tid >> 6, l = tid & 63;
  const int l15 = l & 15, l4 = l >> 4;
  const int wr = w >> 1, wc = w & 1;
  // T1: bijective XCD chunking (requires nwg % 8 == 0)
  const int gx = (int)gridDim.x;
  const int nwg = gx * (int)gridDim.y;
  int lin = (int)blockIdx.y * gx + (int)blockIdx.x;
  lin = (lin & 7) * (nwg >> 3) + (lin >> 3);
  const long bm = (long)(lin / gx) * 128;
  const long bn = (long)(lin % gx) * 128;

  f32x4 acc[4][4] = {};

  const int srow = tid >> 3;            // 0..31 (row within 32-row staging group)
  const int scol = (tid & 7) * 16;      // byte col within 128B row
  const int ssw  = scol ^ ((srow & 7) << 4);  // pre-swizzled source column
  const char* Ab  = (const char*)A;
  const char* Btb = (const char*)Bt;

#define GSTAGE(kt_, buf_)                                                   \
  {                                                                         \
    char* base_ = smem + (buf_) * 32768;                                    \
    _Pragma("unroll")                                                       \
    for (int it = 0; it < 4; ++it) {                                        \
      long arow = bm + it * 32 + srow;                                      \
      GLD16(Ab + (arow * K + (kt_)) * 2 + ssw, base_ + it * 4096 + w * 1024);            \
      long brow = bn + it * 32 + srow;                                      \
      GLD16(Btb + (brow * K + (kt_)) * 2 + ssw, base_ + 16384 + it * 4096 + w * 1024);   \
    }                                                                       \
  }

  GSTAGE(0, 0)

  int cur = 0;
  for (int kt = 0; kt < K; kt += 64) {
    __syncthreads();  // buf[cur] staged (vmcnt drained); prior reads of buf^1 done
    if (kt + 64 < K) GSTAGE(kt + 64, cur ^ 1)
    const char* Ac = smem + cur * 32768;
    const char* Bc = Ac + 16384;
#pragma unroll
    for (int ksub = 0; ksub < 2; ++ksub) {
      short8 aF[4], bF[4];
#pragma unroll
      for (int m = 0; m < 4; ++m) {
        int R = wr * 64 + m * 16 + l15;
        aF[m] = *(const short8*)(Ac + R * 128 + ((ksub * 64 + l4 * 16) ^ ((R & 7) << 4)));
      }
#pragma unroll
      for (int n = 0; n < 4; ++n) {
        int R = wc * 64 + n * 16 + l15;
        bF[n] = *(const short8*)(Bc + R * 128 + ((ksub * 64 + l4 * 16) ^ ((R & 7) << 4)));
      }
#pragma unroll
      for (int m = 0; m < 4; ++m)
#pragma unroll
        for (int n = 0; n < 4; ++n)
          acc[m][n] = __builtin_amdgcn_mfma_f32_16x16x32_bf16(aF[m], bF[n], acc[m][n], 0, 0, 0);
    }
    cur ^= 1;
  }
#undef GSTAGE

#pragma unroll
  for (int m = 0; m < 4; ++m)
#pragma unroll
    for (int n = 0; n < 4; ++n)
#pragma unroll
      for (int r = 0; r < 4; ++r) {
        long row = bm + wr * 64 + m * 16 + l4 * 4 + r;
        long col = bn + wc * 64 + n * 16 + l15;
        float v = acc[m][n][r];
        if constexpr (sizeof(OutT) == 2) {
          C[row * N + col] = __float2bfloat16(v);
        } else {
          C[row * N + col] = v;
        }
      }
}

// ---------------- RoPE + repack (known-good) ----------------
// Q scale folds softmax 1/8 AND log2(e) so attention softmax can use exp2 natively.
__global__ __launch_bounds__(256) void rope_pack(const __hip_bfloat16* __restrict__ qkv,
                                                 __hip_bfloat16* __restrict__ Qb,
                                                 __hip_bfloat16* __restrict__ Kb,
                                                 __hip_bfloat16* __restrict__ VTb) {
  __shared__ __hip_bfloat16 vt[64][72];
  const int bh = blockIdx.x;
  const int b = bh >> 4, h = bh & 15;
  const int t0 = blockIdx.y * 64;
  const int tid = threadIdx.x;
  const float QSCL = 0.125f * 1.4426950408889634f;

#pragma unroll
  for (int rep = 0; rep < 2; ++rep) {
    int idx = rep * 256 + tid;
    int tt = idx >> 3;
    int d0 = (idx & 7) * 8;
    int t = t0 + tt;
    size_t src = ((size_t)(b * T_CTX + t)) * 3072 + h * 64 + d0;
    BV8 qv, kv, vv, qo, ko;
    qv.s = *(const short8*)(qkv + src);
    kv.s = *(const short8*)(qkv + src + 1024);
    vv.s = *(const short8*)(qkv + src + 2048);
#pragma unroll
    for (int p = 0; p < 4; ++p) {
      int i = (d0 >> 1) + p;
      float inv = exp2f(-13.287712379549449f * ((float)(2 * i) * (1.0f / 64.0f)));
      float ang = (float)t * inv;
      float sn, cn;
      sincosf(ang, &sn, &cn);
      float q1 = __bfloat162float(qv.h[2 * p]);
      float q2 = __bfloat162float(qv.h[2 * p + 1]);
      float k1 = __bfloat162float(kv.h[2 * p]);
      float k2 = __bfloat162float(kv.h[2 * p + 1]);
      qo.h[2 * p]     = __float2bfloat16((q1 * cn - q2 * sn) * QSCL);
      qo.h[2 * p + 1] = __float2bfloat16((q1 * sn + q2 * cn) * QSCL);
      ko.h[2 * p]     = __float2bfloat16(k1 * cn - k2 * sn);
      ko.h[2 * p + 1] = __float2bfloat16(k1 * sn + k2 * cn);
    }
    size_t dst = ((size_t)bh * T_CTX + t) * 64 + d0;
    *(short8*)(Qb + dst) = qo.s;
    *(short8*)(Kb + dst) = ko.s;
#pragma unroll
    for (int j = 0; j < 8; ++j) vt[d0 + j][tt] = vv.h[j];
  }
  __syncthreads();
#pragma unroll
  for (int rep = 0; rep < 2; ++rep) {
    int idx = rep * 256 + tid;
    int d = idx >> 3;
    int toff = (idx & 7) * 8;
    BV8 o;
#pragma unroll
    for (int j = 0; j < 8; ++j) o.h[j] = vt[d][toff + j];
    *(short8*)(VTb + ((size_t)bh * 64 + d) * T_CTX + t0 + toff) = o.s;
  }
}

// ---------------- flash attention (causal), 32x32 MFMA, paired-tile barriers ----------------
// (round-12 known-good: 4 waves = qsub x kh, 64-row balanced slab pairs, k-split,
// fixed-base exp2 softmax, end-of-kernel merge, two KV tiles per barrier)
__global__ __launch_bounds__(256) void flash_attn(const __hip_bfloat16* __restrict__ Qb,
                                                  const __hip_bfloat16* __restrict__ Kb,
                                                  const __hip_bfloat16* __restrict__ VTb,
                                                  __hip_bfloat16* __restrict__ Y) {
  __shared__ __align__(16) char smem[65536];
  const int bh = blockIdx.x;
  const int b = bh >> 4, h = bh & 15;
  const int y = blockIdx.y;
  const int jA = 31 - y;
  const int jB = y;
  const int tid = threadIdx.x;
  const int w = tid >> 6, l = tid & 63;
  const int qsub = w >> 1, kh = w & 1;
  const int l31 = l & 31, hh = l >> 5;
  const int sw7 = (l31 & 7) << 4;
  const int rowb = tid >> 3;
  const int colS = (tid & 7) * 16;

#define STAGE1(gg)                                                                     \
  {                                                                                    \
    const int tt_ = ((gg) <= jA) ? (gg) : (gg) - jA - 1;                               \
    const int kv0_ = tt_ << 6;                                                         \
    char* base_ = smem + (((gg) >> 1) & 1) * 32768 + ((gg) & 1) * 16384;               \
    _Pragma("unroll")                                                                  \
    for (int rnd = 0; rnd < 2; ++rnd) {                                                \
      int row = rnd * 32 + rowb;                                                       \
      int sw = colS ^ ((row & 7) << 4);                                                \
      GLD16((const char*)Kb + (((size_t)bh * T_CTX + kv0_ + row) << 7) + sw,           \
            base_ + rnd * 4096 + w * 1024);                                            \
      GLD16((const char*)VTb + ((((size_t)bh * 64 + row) * T_CTX + kv0_) << 1) + sw,   \
            base_ + 8192 + rnd * 4096 + w * 1024);                                     \
    }                                                                                  \
  }

  f32x16 oA0 = {}, oA1 = {}, oB0 = {}, oB1 = {};
  float lrA = 0.0f, lrB = 0.0f;

  STAGE1(0)
  STAGE1(1)

  int rr = 0;
#pragma unroll
  for (int ph = 0; ph < 2; ++ph) {
    const int j = ph ? jB : jA;
    const int qglob = j * 64 + qsub * 32 + l31;
    f32x16& od0 = ph ? oB0 : oA0;
    f32x16& od1 = ph ? oB1 : oA1;
    float& lrw = ph ? lrB : lrA;

    short8 qB[4];
#pragma unroll
    for (int dblk = 0; dblk < 4; ++dblk)
      qB[dblk] = *(const short8*)(Qb + ((size_t)bh * T_CTX + qglob) * 64 + dblk * 16 + hh * 8);

    for (int t = 0; t <= j; ++t, ++rr) {
      if ((rr & 1) == 0) {
        __syncthreads();
        if (rr + 2 <= 32) STAGE1(rr + 2)
        if (rr + 3 <= 32) STAGE1(rr + 3)
      }
      const char* KsB = smem + ((rr >> 1) & 1) * 32768 + (rr & 1) * 16384;
      const char* VsB = KsB + 8192;
      const int kv0 = t << 6;
      const bool lastT = (t == j);

      if (!(lastT && kh > qsub)) {
        short8 kA[4];
#pragma unroll
        for (int dblk = 0; dblk < 4; ++dblk)
          kA[dblk] = *(const short8*)(KsB + (kh * 32 + l31) * 128 + ((dblk * 32 + hh * 16) ^ sw7));
        short8 vA[2][2];
#pragma unroll
        for (int dt = 0; dt < 2; ++dt)
#pragma unroll
          for (int ks = 0; ks < 2; ++ks)
            vA[dt][ks] = *(const short8*)(VsB + (dt * 32 + l31) * 128 +
                                          ((kh * 64 + ks * 32 + hh * 16) ^ sw7));

        f32x16 sT = {};
#pragma unroll
        for (int dblk = 0; dblk < 4; ++dblk) {
          __builtin_amdgcn_s_setprio(1);
          sT = __builtin_amdgcn_mfma_f32_32x32x16_bf16(kA[dblk], qB[dblk], sT, 0, 0, 0);
          __builtin_amdgcn_s_setprio(0);
        }
        if (lastT && kh == qsub) {
          const int kbase = kv0 + kh * 32 + 4 * hh;
#pragma unroll
          for (int r = 0; r < 16; ++r) {
            int kg = kbase + (r & 3) + 8 * (r >> 2);
            sT[r] = (kg > qglob) ? -1e30f : sT[r];
          }
        }
        float s8[8];
#pragma unroll
        for (int i = 0; i < 8; ++i) {
          sT[i]     = __builtin_amdgcn_exp2f(sT[i]);
          sT[i + 8] = __builtin_amdgcn_exp2f(sT[i + 8]);
          s8[i] = sT[i] + sT[i + 8];
        }
        float ps = ((s8[0] + s8[1]) + (s8[2] + s8[3])) + ((s8[4] + s8[5]) + (s8[6] + s8[7]));
        ps += __shfl_xor(ps, 32);
        lrw += ps;
        uint32_t wk[8];
#pragma unroll
        for (int i = 0; i < 8; ++i) wk[i] = pkbf(sT[2 * i], sT[2 * i + 1]);
#pragma unroll
        for (int ks = 0; ks < 2; ++ks) {
          const int base = ks * 4;
          uint32_t own0 = wk[base + 0], own1 = wk[base + 1];
          uint32_t own2 = wk[base + 2], own3 = wk[base + 3];
          uint32_t e0 = (uint32_t)__shfl_xor((int)(hh ? own0 : own2), 32);
          uint32_t e1 = (uint32_t)__shfl_xor((int)(hh ? own1 : own3), 32);
          U32x4 u;
          u.u[0] = hh ? e0 : own0;
          u.u[1] = hh ? e1 : own1;
          u.u[2] = hh ? own2 : e0;
          u.u[3] = hh ? own3 : e1;
          __builtin_amdgcn_s_setprio(1);
          od0 = __builtin_amdgcn_mfma_f32_32x32x16_bf16(vA[0][ks], u.s8, od0, 0, 0, 0);
          od1 = __builtin_amdgcn_mfma_f32_32x32x16_bf16(vA[1][ks], u.s8, od1, 0, 0, 0);
          __builtin_amdgcn_s_setprio(0);
        }
      }
    }
  }

  __syncthreads();
  {
    float* exch = (float*)smem;
    float* lst = exch + 8192;
    const int slotA = (0 * 2 + qsub) * 2 + kh;
    const int slotB = (1 * 2 + qsub) * 2 + kh;
    const f32x16& nA = kh ? oA0 : oA1;
    const f32x16& nB = kh ? oB0 : oB1;
#pragma unroll
    for (int m = 0; m < 4; ++m) {
      int c = ((2 * m + hh) ^ (l31 & 7)) * 4;
      f32x4 va, vb;
#pragma unroll
      for (int i = 0; i < 4; ++i) { va[i] = nA[m * 4 + i]; vb[i] = nB[m * 4 + i]; }
      *(f32x4*)(exch + slotA * 1024 + l31 * 32 + c) = va;
      *(f32x4*)(exch + slotB * 1024 + l31 * 32 + c) = vb;
    }
    if (hh == 0) {
      lst[slotA * 32 + l31] = lrA;
      lst[slotB * 32 + l31] = lrB;
    }
    __syncthreads();
    const int pA = (0 * 2 + qsub) * 2 + (kh ^ 1);
    const int pB = (1 * 2 + qsub) * 2 + (kh ^ 1);
    float ltA = lrA + lst[pA * 32 + l31];
    float ltB = lrB + lst[pB * 32 + l31];
    f32x16& ownA = kh ? oA1 : oA0;
    f32x16& ownB = kh ? oB1 : oB0;
#pragma unroll
    for (int m = 0; m < 4; ++m) {
      int c = ((2 * m + hh) ^ (l31 & 7)) * 4;
      f32x4 aA = *(const f32x4*)(exch + pA * 1024 + l31 * 32 + c);
      f32x4 aB = *(const f32x4*)(exch + pB * 1024 + l31 * 32 + c);
#pragma unroll
      for (int i = 0; i < 4; ++i) { ownA[m * 4 + i] += aA[i]; ownB[m * 4 + i] += aB[i]; }
    }
#pragma unroll
    for (int sl = 0; sl < 2; ++sl) {
      const f32x16& ov = sl ? ownB : ownA;
      float inv = 1.0f / (sl ? ltB : ltA);
      int q0s = (sl ? jB : jA) * 64 + qsub * 32;
      size_t rowoff = ((size_t)(b * T_CTX + q0s + l31)) * DIM_C + h * 64 + kh * 32;
#pragma unroll
      for (int m = 0; m < 4; ++m) {
        union { ushort4 v; unsigned short us[4]; } st;
#pragma unroll
        for (int i = 0; i < 4; ++i) {
          union { __hip_bfloat16 h2; unsigned short u; } cv;
          cv.h2 = __float2bfloat16(ov[m * 4 + i] * inv);
          st.us[i] = cv.u;
        }
        *(ushort4*)(Y + rowoff + 8 * m + 4 * hh) = st.v;
      }
    }
  }
#undef STAGE1
}

// ---------------- launcher ----------------
extern "C" void kernel_launch(void* const* d_in, const int* in_sizes, int n_in,
                              void* d_out, int out_size, void* d_ws, size_t ws_size,
                              hipStream_t stream) {
  const float* x     = (const float*)d_in[0];
  const float* qkv_w = (const float*)d_in[1];
  const float* out_w = (const float*)d_in[2];
  float* out = (float*)d_out;

  char* ws = (char*)d_ws;
  const size_t MB = 1024 * 1024;
  __hip_bfloat16* xb    = (__hip_bfloat16*)(ws + 0 * MB);
  __hip_bfloat16* wqkvb = (__hip_bfloat16*)(ws + 8 * MB);
  __hip_bfloat16* woutb = (__hip_bfloat16*)(ws + 14 * MB);
  __hip_bfloat16* qkvb  = (__hip_bfloat16*)(ws + 16 * MB);
  __hip_bfloat16* Qb    = (__hip_bfloat16*)(ws + 40 * MB);
  __hip_bfloat16* Kb    = (__hip_bfloat16*)(ws + 48 * MB);
  __hip_bfloat16* VTb   = (__hip_bfloat16*)(ws + 56 * MB);
  __hip_bfloat16* yb    = (__hip_bfloat16*)(ws + 64 * MB);

  // single fused convert launch
  cvt_all<<<8192, 256, 0, stream>>>(x, qkv_w, out_w, xb, wqkvb, woutb);

  // qkv = x @ qkv_w^T (BK=64, double-buffered)
  gemm_bt<__hip_bfloat16><<<dim3(24, 32), 256, 0, stream>>>(xb, wqkvb, qkvb, 4096, 3072, 1024);

  rope_pack<<<dim3(32, 32), 256, 0, stream>>>(qkvb, Qb, Kb, VTb);

  // 16 slab-pairs (31-y, y of 64-row slabs) x 32 bh = 512 blocks, 4 waves each
  flash_attn<<<dim3(NBH, 16), 256, 0, stream>>>(Qb, Kb, VTb, yb);

  // out = y @ out_w^T (BK=64, double-buffered, fp32 out)
  gemm_bt<float><<<dim3(8, 32), 256, 0, stream>>>(yb, woutb, out, 4096, 1024, 1024);
}